// Round 7
// baseline (311.343 us; speedup 1.0000x reference)
//
#include <hip/hip_runtime.h>
#include <hip/hip_bf16.h>
#include <math.h>

#define Bv 2
#define Tv 2048
#define Cv 1024
#define Hv 16
#define DHv 64
#define BTv (Bv*Tv)

typedef unsigned short u16;
typedef unsigned int u32;
typedef __attribute__((ext_vector_type(8))) short short8;
typedef __attribute__((ext_vector_type(4))) float f32x4;

#define GLOAD16(g,l) __builtin_amdgcn_global_load_lds((const __attribute__((address_space(1))) void*)(g), (__attribute__((address_space(3))) void*)(l), 16, 0, 0)

__device__ __forceinline__ u16 f2bf(float f) {
    u32 r; asm("v_cvt_pk_bf16_f32 %0, %1, %1" : "=v"(r) : "v"(f)); return (u16)r;
}
__device__ __forceinline__ u32 pk2bf(float a, float b) {
    u32 r; asm("v_cvt_pk_bf16_f32 %0, %1, %2" : "=v"(r) : "v"(a), "v"(b)); return r;
}
__device__ __forceinline__ float fexp2(float x) {
    float r; asm("v_exp_f32 %0, %1" : "=v"(r) : "v"(x)); return r;
}

// ---------------- fuse mix into weights (block per (sel,d)) + proj cvt ----------------
__global__ __launch_bounds__(256) void fuse_w_kernel(
    const float* __restrict__ wq, const float* __restrict__ wk, const float* __restrict__ wv,
    const float* __restrict__ wp,
    const float* __restrict__ mq, const float* __restrict__ mk, const float* __restrict__ mv,
    u16* __restrict__ whi, u16* __restrict__ cpj)
{
    int blk = blockIdx.x;
    int tid = threadIdx.x;
    if (blk >= 192) {          // proj weight f32 -> bf16: 16 blocks x 64 rows
        size_t base = (size_t)(blk - 192) * 65536;
        for (int i = tid; i < 16384; i += 256) {
            float4 v = *(const float4*)&wp[base + (size_t)i*4];
            *(uint2*)&cpj[base + (size_t)i*4] = make_uint2(pk2bf(v.x,v.y), pk2bf(v.z,v.w));
        }
        return;
    }
    int sel = blk >> 6, d = blk & 63;
    const float* w   = sel==0 ? wq : (sel==1 ? wk : wv);
    const float* mix = sel==0 ? mq : (sel==1 ? mk : mv);
    int c0 = tid * 4;
    float4 wrow[16];
#pragma unroll
    for (int m=0;m<16;++m) wrow[m] = *(const float4*)&w[(size_t)(m*64 + d)*1024 + c0];
#pragma unroll
    for (int h=0;h<16;++h) {
        float ax=0.f, ay=0.f, az=0.f, aw=0.f;
#pragma unroll
        for (int m=0;m<16;++m) {
            float mv_ = mix[h*16 + m];
            ax += mv_*wrow[m].x; ay += mv_*wrow[m].y; az += mv_*wrow[m].z; aw += mv_*wrow[m].w;
        }
        *(uint2*)&whi[(size_t)((sel*16 + h)*64 + d)*1024 + c0] = make_uint2(pk2bf(ax,ay), pk2bf(az,aw));
    }
}

// ---------------- x -> bf16 ----------------
__global__ __launch_bounds__(256) void xcvt_kernel(const float* __restrict__ xf, u16* __restrict__ xb)
{
    int i = blockIdx.x*256 + threadIdx.x;     // i < BTv*Cv/4
    float4 v = ((const float4*)xf)[i];
    ((uint2*)xb)[i] = make_uint2(pk2bf(v.x,v.y), pk2bf(v.z,v.w));
}

// ---------------- bf16 MFMA GEMM (m97-style + XCD chunk swizzle) ----------------
// Y[M,N] = X[M,K]*W[N,K]^T, f32 out. BK=64, gload_lds w16 pre-swizzled src; 1D grid.
template<int BM, int BN>
__global__ __launch_bounds__(256) void gemm_bf16_kernel(
    const u16* __restrict__ X, const u16* __restrict__ W, float* __restrict__ Y,
    int M, int N, int K)
{
    constexpr int MR = BM/32, NR = BN/32;
    constexpr int ACALLS = (BM*8)/256, BCALLS = (BN*8)/256;
    __shared__ __align__(16) u16 As[BM*64];
    __shared__ __align__(16) u16 Bs[BN*64];
    int tid = threadIdx.x;
    int wv = tid >> 6, lane = tid & 63;
    int wr = wv >> 1, wc = wv & 1;
    int c = lane & 15, g = lane >> 4;

    // bijective XCD chunk swizzle (m204): contiguous wg range per XCD, N-tile-major
    int mtiles = M / BM;
    int nwg = gridDim.x;
    int qd = nwg >> 3, rr_ = nwg & 7;
    int xcd = blockIdx.x & 7, idx = blockIdx.x >> 3;
    int wg = (xcd < rr_ ? xcd*(qd+1) : rr_*(qd+1) + (xcd-rr_)*qd) + idx;
    int bm = (wg % mtiles) * BM, bn = (wg / mtiles) * BN;

    int r_ = tid >> 3, s_ = tid & 7;

    f32x4 acc[MR][NR];
#pragma unroll
    for (int i=0;i<MR;++i)
#pragma unroll
        for (int j=0;j<NR;++j) acc[i][j] = (f32x4){0.f,0.f,0.f,0.f};

    for (int k0 = 0; k0 < K; k0 += 64) {
#pragma unroll
        for (int i=0;i<ACALLS;++i) {
            int row = i*32 + r_;
            GLOAD16(X + (size_t)(bm+row)*K + k0 + ((s_ ^ (row&7))*8),
                    (u16*)As + i*2048 + wv*512);
        }
#pragma unroll
        for (int i=0;i<BCALLS;++i) {
            int row = i*32 + r_;
            GLOAD16(W + (size_t)(bn+row)*K + k0 + ((s_ ^ (row&7))*8),
                    (u16*)Bs + i*2048 + wv*512);
        }
        __syncthreads();          // drains vmcnt(0): tile landed
#pragma unroll
        for (int kh=0; kh<2; ++kh) {
            short8 a[MR], b[NR];
#pragma unroll
            for (int i=0;i<MR;++i) {
                int row = wr*(BM/2) + i*16 + c;
                a[i] = *(const short8*)&As[row*64 + (((kh*4+g) ^ (c&7))*8)];
            }
#pragma unroll
            for (int j=0;j<NR;++j) {
                int row = wc*(BN/2) + j*16 + c;
                b[j] = *(const short8*)&Bs[row*64 + (((kh*4+g) ^ (c&7))*8)];
            }
#pragma unroll
            for (int i=0;i<MR;++i)
#pragma unroll
                for (int j=0;j<NR;++j)
                    acc[i][j] = __builtin_amdgcn_mfma_f32_16x16x32_bf16(a[i], b[j], acc[i][j], 0,0,0);
        }
        __syncthreads();          // all reads done before next stage overwrites
    }
#pragma unroll
    for (int i=0;i<MR;++i)
#pragma unroll
        for (int j=0;j<NR;++j)
#pragma unroll
            for (int rr=0;rr<4;++rr)
                Y[(size_t)(bm + wr*(BM/2) + i*16 + g*4 + rr)*N + bn + wc*(BN/2) + j*16 + c] = acc[i][j][rr];
}

// ---------------- gates + RoPE + RMS-norm + k time-shift -> bf16 [b,h,t,d] ----------------
__global__ __launch_bounds__(256) void post_kernel(
    const float* __restrict__ x, const float* __restrict__ ve,
    const float* __restrict__ cosT, const float* __restrict__ sinT,
    const float* __restrict__ vegw, const float* __restrict__ atgw,
    float* __restrict__ qkv, float* __restrict__ gateA,
    u16* __restrict__ qbf, u16* __restrict__ kbf)
{
    int bt = blockIdx.x;
    int b = bt >> 11;
    int t = bt & (Tv-1);
    int wave = threadIdx.x >> 6;
    int lane = threadIdx.x & 63;
    int h = blockIdx.y*4 + wave;
    size_t base = (size_t)bt*3072 + h*DHv;
    size_t bh = (size_t)b*Hv + h;

    float gv  = (lane < 32) ? x[(size_t)bt*Cv + lane] * vegw[h*32 + lane] : 0.f;
    float gaP = (lane < 12) ? x[(size_t)bt*Cv + lane] * atgw[h*12 + lane] : 0.f;
#pragma unroll
    for (int off=32; off; off>>=1) {
        gv  += __shfl_xor(gv,  off);
        gaP += __shfl_xor(gaP, off);
    }
    float gateV = 2.f / (1.f + expf(-gv));
    float ga    = 1.f / (1.f + expf(-gaP));
    if (lane == 0) gateA[(size_t)bt*Hv + h] = ga;

    qkv[base + 2048 + lane] += gateV * ve[(size_t)bt*Cv + h*DHv + lane];

    float cs = cosT[t*32 + (lane & 31)];
    float sn = sinT[t*32 + (lane & 31)];

    float qa = qkv[base + lane];
    float qb = __shfl_xor(qa, 32);
    float qr = qa*cs + ((lane < 32) ? qb*sn : -qb*sn);
    float ss = qr*qr;
#pragma unroll
    for (int off=32; off; off>>=1) ss += __shfl_xor(ss, off);
    float qn = qr * rsqrtf(ss*(1.f/64.f) + 1e-6f);
    qbf[(bh*Tv + t)*DHv + lane] = f2bf(qn);

    float ka = qkv[base + 1024 + lane];
    float kb = __shfl_xor(ka, 32);
    float kr = ka*cs + ((lane < 32) ? kb*sn : -kb*sn);
    float s2 = kr*kr;
#pragma unroll
    for (int off=32; off; off>>=1) s2 += __shfl_xor(s2, off);
    float kn = kr * rsqrtf(s2*(1.f/64.f) + 1e-6f);
    if (lane < 32) {
        kbf[(bh*Tv + t)*DHv + lane] = f2bf(kn);
    } else {
        if (t == 0)   kbf[(bh*Tv + 0)*DHv + lane] = f2bf(kn);
        if (t+1 < Tv) kbf[(bh*Tv + t + 1)*DHv + lane] = f2bf(kn);
    }
}

// ---------------- V transpose: f32 qkv v-part -> bf16 [b,h,d,t] ----------------
__global__ __launch_bounds__(256) void vt_kernel(
    const float* __restrict__ qkv, u16* __restrict__ vT)
{
    __shared__ float Ls[64][65];
    int t0 = blockIdx.x * 64;
    int h  = blockIdx.y;
    int b  = blockIdx.z;
    int tid = threadIdx.x;
    for (int i = tid; i < 4096; i += 256) {
        int tt = i >> 6, d = i & 63;
        Ls[tt][d] = qkv[((size_t)(b*Tv + t0 + tt))*3072 + 2048 + h*DHv + d];
    }
    __syncthreads();
    size_t ob = ((size_t)(b*Hv + h))*DHv;
    for (int i = tid; i < 4096; i += 256) {
        int dv = i >> 6, tt = i & 63;
        vT[(ob + dv)*Tv + t0 + tt] = f2bf(Ls[tt][dv]);
    }
}

// ---------------- MFMA flash attention: split-K 2-way, partial O/L out ----------------
__global__ __launch_bounds__(256) void attn_mfma_kernel(
    const u16* __restrict__ qbf, const u16* __restrict__ kbf,
    const u16* __restrict__ vT,
    float* __restrict__ Opart, float* __restrict__ Lpart,
    const int* __restrict__ wptr)
{
    __shared__ __align__(16) u16 Ks[2][64*64];
    __shared__ __align__(16) u16 Vt[2][64*64];
    __shared__ __align__(16) u16 Pl[4][32][76];   // 52224 B total -> 3 blocks/CU

    int bx = blockIdx.x;
    int half = bx & 1;
    int qtile = (int)(gridDim.x >> 1) - 1 - (bx >> 1);   // longest-first
    int h = blockIdx.y, b = blockIdx.z;
    int tid = threadIdx.x, wvi = tid >> 6, lane = tid & 63;
    int c = lane & 15, g = lane >> 4;
    int qbase = qtile*128 + wvi*32;
    int wsz = *wptr;
    bool use_w = !(wsz < 0 || wsz >= Tv-1);

    size_t bh = (size_t)b*Hv + h;
    const u16* qb = qbf + (bh*(size_t)Tv + qbase)*DHv;
    short8 A[2][2];
#pragma unroll
    for (int rb=0; rb<2; ++rb)
#pragma unroll
        for (int kh=0; kh<2; ++kh)
            A[rb][kh] = *(const short8*)(qb + (size_t)(rb*16+c)*DHv + kh*32 + g*8);

    f32x4 zero4 = {0.f,0.f,0.f,0.f};
    f32x4 O[2][4], L[2];
#pragma unroll
    for (int rb=0;rb<2;++rb){ L[rb]=zero4;
#pragma unroll
        for (int dg=0;dg<4;++dg) O[rb][dg]=zero4; }

    short8 ONES;
#pragma unroll
    for (int i=0;i<8;++i) ONES[i] = (short)0x3F80;   // bf16 1.0

    int kt_hi = qtile*2 + 1;
    int kt_lo = 0;
    if (use_w) { int lo = qtile*128 - wsz; if (lo > 0) kt_lo = lo >> 6; }
    int s0 = kt_lo + half;                 // this half's first k-tile (stride 2)
    const float C1 = 0.18033688f;    // 0.125 * log2(e)
    const float C2 = -11.5415606f;   // -8 * log2(e)

    const u16* gK = kbf + bh*(size_t)Tv*DHv;
    const u16* gV = vT  + bh*(size_t)(DHv*Tv);
    int r_ = tid >> 3, s_ = tid & 7;
    int r0 = r_, r1 = r_ + 32;

    auto stage = [&](int buf, int kt) {   // async: 4 gload_lds per wave, pre-swizzled src
        GLOAD16(gK + (size_t)kt*4096 + r0*64 + ((s_ ^ (r0&7))*8), (u16*)&Ks[buf][0] + wvi*512);
        GLOAD16(gK + (size_t)kt*4096 + r1*64 + ((s_ ^ (r1&7))*8), (u16*)&Ks[buf][0] + 2048 + wvi*512);
        GLOAD16(gV + (size_t)r0*Tv + kt*64 + ((s_ ^ (r0&7))*8),   (u16*)&Vt[buf][0] + wvi*512);
        GLOAD16(gV + (size_t)r1*Tv + kt*64 + ((s_ ^ (r1&7))*8),   (u16*)&Vt[buf][0] + 2048 + wvi*512);
    };

    auto compute = [&](int kt, int cur) {
        short8 Bk[4][2];
#pragma unroll
        for (int kg=0;kg<4;++kg)
#pragma unroll
            for (int kh=0;kh<2;++kh)
                Bk[kg][kh] = *(const short8*)&Ks[cur][(kg*16+c)*64 + (((kh*4+g) ^ (c&7))*8)];
        f32x4 S[2][4];
        __builtin_amdgcn_s_setprio(1);
#pragma unroll
        for (int rb=0;rb<2;++rb)
#pragma unroll
            for (int kg=0;kg<4;++kg) {
                S[rb][kg] = __builtin_amdgcn_mfma_f32_16x16x32_bf16(A[rb][0], Bk[kg][0], zero4, 0,0,0);
                S[rb][kg] = __builtin_amdgcn_mfma_f32_16x16x32_bf16(A[rb][1], Bk[kg][1], S[rb][kg], 0,0,0);
            }
        __builtin_amdgcn_s_setprio(0);
        bool needmask = (kt*64 + 63 > qbase) || (use_w && (kt*64 < qbase + 31 - wsz));
#pragma unroll
        for (int rb=0;rb<2;++rb)
#pragma unroll
            for (int kg=0;kg<4;++kg)
#pragma unroll
                for (int r=0;r<4;++r) {
                    float t = fmaf(S[rb][kg][r], C1, C2);   // exp2 domain
                    if (needmask) {
                        int key = kt*64 + kg*16 + c;
                        int qg  = qbase + rb*16 + g*4 + r;
                        bool ok = (key <= qg) && (!use_w || (qg - key <= wsz));
                        t = ok ? t : -1e30f;
                    }
                    Pl[wvi][rb*16 + g*4 + r][kg*16 + c] = f2bf(fexp2(t));
                }
        asm volatile("s_waitcnt lgkmcnt(0)" ::: "memory");
        __builtin_amdgcn_sched_barrier(0);
        short8 Vf[4][2];
#pragma unroll
        for (int dg=0;dg<4;++dg)
#pragma unroll
            for (int kh=0;kh<2;++kh)
                Vf[dg][kh] = *(const short8*)&Vt[cur][(dg*16+c)*64 + (((kh*4+g) ^ (c&7))*8)];
        __builtin_amdgcn_s_setprio(1);
#pragma unroll
        for (int rb=0;rb<2;++rb) {
            short8 PA0 = *(const short8*)&Pl[wvi][rb*16+c][g*8];
            short8 PA1 = *(const short8*)&Pl[wvi][rb*16+c][32 + g*8];
            L[rb] = __builtin_amdgcn_mfma_f32_16x16x32_bf16(PA0, ONES, L[rb], 0,0,0);
            L[rb] = __builtin_amdgcn_mfma_f32_16x16x32_bf16(PA1, ONES, L[rb], 0,0,0);
#pragma unroll
            for (int dg=0;dg<4;++dg) {
                O[rb][dg] = __builtin_amdgcn_mfma_f32_16x16x32_bf16(PA0, Vf[dg][0], O[rb][dg], 0,0,0);
                O[rb][dg] = __builtin_amdgcn_mfma_f32_16x16x32_bf16(PA1, Vf[dg][1], O[rb][dg], 0,0,0);
            }
        }
        __builtin_amdgcn_s_setprio(0);
    };

    if (s0 <= kt_hi) stage(0, s0);
    __syncthreads();
    int cur = 0;
    for (int kt = s0; kt <= kt_hi; kt += 2) {
        if (kt + 2 <= kt_hi) stage(cur^1, kt+2);   // loads fly across compute
        compute(kt, cur);
        __syncthreads();                           // drains vmcnt(0) + lgkm + barrier
        cur ^= 1;
    }

    // partial outputs: O (f32, un-normalized, un-gated) and L
    float* Ob = Opart + (size_t)half * BTv * Cv;
    float* Lb = Lpart + (size_t)half * BTv * Hv;
#pragma unroll
    for (int rb=0;rb<2;++rb) {
        if (c == 0)
#pragma unroll
            for (int r=0;r<4;++r)
                Lb[(size_t)(b*Tv + qbase + rb*16 + g*4 + r)*Hv + h] = L[rb][r];
#pragma unroll
        for (int dg=0;dg<4;++dg)
#pragma unroll
            for (int r=0;r<4;++r)
                Ob[((size_t)(b*Tv + qbase + rb*16 + g*4 + r))*Cv + h*DHv + dg*16 + c] = O[rb][dg][r];
    }
}

// ---------------- combine: ybf = (O0+O1) * ga / (L0+L1) ----------------
__global__ __launch_bounds__(256) void combine_kernel(
    const float* __restrict__ Opart, const float* __restrict__ Lpart,
    const float* __restrict__ gateA, u16* __restrict__ ybf)
{
    int i4 = blockIdx.x*256 + threadIdx.x;     // over BTv*Cv/4 float4s
    int row = i4 >> 8;                          // Cv/4 = 256 float4 per row
    int col = (i4 & 255) << 2;
    int h = col >> 6;
    float l0 = Lpart[(size_t)row*Hv + h];
    float l1 = Lpart[(size_t)(BTv*Hv) + (size_t)row*Hv + h];
    float s = gateA[(size_t)row*Hv + h] / (l0 + l1);
    float4 a = *(const float4*)&Opart[(size_t)i4*4];
    float4 b = *(const float4*)&Opart[(size_t)(BTv*Cv) + (size_t)i4*4];
    *(uint2*)&ybf[(size_t)i4*4] =
        make_uint2(pk2bf((a.x+b.x)*s, (a.y+b.y)*s), pk2bf((a.z+b.z)*s, (a.w+b.w)*s));
}

extern "C" void kernel_launch(void* const* d_in, const int* in_sizes, int n_in,
                              void* d_out, int out_size, void* d_ws, size_t ws_size,
                              hipStream_t stream) {
    const float* x    = (const float*)d_in[0];
    const float* ve   = (const float*)d_in[1];
    const float* cosT = (const float*)d_in[2];
    const float* sinT = (const float*)d_in[3];
    const float* cqw  = (const float*)d_in[4];
    const float* ckw  = (const float*)d_in[5];
    const float* cvw  = (const float*)d_in[6];
    const float* cpw  = (const float*)d_in[7];
    const float* vegw = (const float*)d_in[8];
    const float* atgw = (const float*)d_in[9];
    const float* qmix = (const float*)d_in[10];
    const float* kmix = (const float*)d_in[11];
    const float* vmix = (const float*)d_in[12];
    const int*   wsz  = (const int*)d_in[13];
    float* out = (float*)d_out;

    const size_t M1 = 1u << 20;
    float* p0 = (float*)d_ws;
    // [0,12M) floats: qkv f32 (phase B) -> reused phase C as:
    //   Opart [0, 8.4M) | ybf bf16 at [8.4M, 10.5M) | Lpart [10.5M, 11M)
    float* qkv = p0;
    u16*   cpj = (u16*)(p0 + 12*M1);
    float* ga  = p0 + 12*M1 + M1/2;
    u16*   qbf = (u16*)(p0 + 13*M1);
    u16*   kbf = (u16*)(p0 + 15*M1);
    u16*   vT  = (u16*)(p0 + 17*M1);
    u16*   whi = (u16*)(p0 + 13*M1);
    u16*   xbf = (u16*)(p0 + 15*M1);
    float* Opart = p0;                                   // 2 x BT*C f32 = 33.6 MB
    u16*   ybf   = (u16*)(p0 + (size_t)2*BTv*Cv);
    float* Lpart = p0 + (size_t)2*BTv*Cv + (size_t)BTv*Cv/2;

    fuse_w_kernel<<<208, 256, 0, stream>>>(cqw, ckw, cvw, cpw, qmix, kmix, vmix, whi, cpj);
    xcvt_kernel<<<(BTv*Cv/4)/256, 256, 0, stream>>>(x, xbf);

    gemm_bf16_kernel<128,128><<<(3072/128)*(BTv/128), 256, 0, stream>>>(
        xbf, whi, qkv, BTv, 3072, Cv);

    post_kernel<<<dim3(BTv, Hv/4), 256, 0, stream>>>(x, ve, cosT, sinT, vegw, atgw,
                                                     qkv, ga, qbf, kbf);

    vt_kernel<<<dim3(Tv/64, Hv, Bv), 256, 0, stream>>>(qkv, vT);

    attn_mfma_kernel<<<dim3(2*(Tv/128), Hv, Bv), 256, 0, stream>>>(
        qbf, kbf, vT, Opart, Lpart, wsz);

    combine_kernel<<<(BTv*Cv/4)/256, 256, 0, stream>>>(Opart, Lpart, ga, ybf);

    gemm_bf16_kernel<128,64><<<(Cv/64)*(BTv/128), 256, 0, stream>>>(
        ybf, cpj, out, BTv, Cv, Cv);
}

// Round 10
// 300.312 us; speedup vs baseline: 1.0367x; 1.0367x over previous
//
#include <hip/hip_runtime.h>
#include <hip/hip_bf16.h>
#include <math.h>

#define Bv 2
#define Tv 2048
#define Cv 1024
#define Hv 16
#define DHv 64
#define BTv (Bv*Tv)

typedef unsigned short u16;
typedef unsigned int u32;
typedef __attribute__((ext_vector_type(8))) short short8;
typedef __attribute__((ext_vector_type(4))) float f32x4;

#define GLOAD16(g,l) __builtin_amdgcn_global_load_lds((const __attribute__((address_space(1))) void*)(g), (__attribute__((address_space(3))) void*)(l), 16, 0, 0)

__device__ __forceinline__ u16 f2bf(float f) {
    u32 r; asm("v_cvt_pk_bf16_f32 %0, %1, %1" : "=v"(r) : "v"(f)); return (u16)r;
}
__device__ __forceinline__ u32 pk2bf(float a, float b) {
    u32 r; asm("v_cvt_pk_bf16_f32 %0, %1, %2" : "=v"(r) : "v"(a), "v"(b)); return r;
}
__device__ __forceinline__ float fexp2(float x) {
    float r; asm("v_exp_f32 %0, %1" : "=v"(r) : "v"(x)); return r;
}

// ---------------- fuse mix into weights (block per (sel,d)) + proj cvt ----------------
__global__ __launch_bounds__(256) void fuse_w_kernel(
    const float* __restrict__ wq, const float* __restrict__ wk, const float* __restrict__ wv,
    const float* __restrict__ wp,
    const float* __restrict__ mq, const float* __restrict__ mk, const float* __restrict__ mv,
    u16* __restrict__ whi, u16* __restrict__ cpj)
{
    int blk = blockIdx.x;
    int tid = threadIdx.x;
    if (blk >= 192) {          // proj weight f32 -> bf16: 16 blocks x 64 rows
        size_t base = (size_t)(blk - 192) * 65536;
        for (int i = tid; i < 16384; i += 256) {
            float4 v = *(const float4*)&wp[base + (size_t)i*4];
            *(uint2*)&cpj[base + (size_t)i*4] = make_uint2(pk2bf(v.x,v.y), pk2bf(v.z,v.w));
        }
        return;
    }
    int sel = blk >> 6, d = blk & 63;
    const float* w   = sel==0 ? wq : (sel==1 ? wk : wv);
    const float* mix = sel==0 ? mq : (sel==1 ? mk : mv);
    int c0 = tid * 4;
    float4 wrow[16];
#pragma unroll
    for (int m=0;m<16;++m) wrow[m] = *(const float4*)&w[(size_t)(m*64 + d)*1024 + c0];
#pragma unroll
    for (int h=0;h<16;++h) {
        float ax=0.f, ay=0.f, az=0.f, aw=0.f;
#pragma unroll
        for (int m=0;m<16;++m) {
            float mv_ = mix[h*16 + m];
            ax += mv_*wrow[m].x; ay += mv_*wrow[m].y; az += mv_*wrow[m].z; aw += mv_*wrow[m].w;
        }
        *(uint2*)&whi[(size_t)((sel*16 + h)*64 + d)*1024 + c0] = make_uint2(pk2bf(ax,ay), pk2bf(az,aw));
    }
}

// ---------------- x -> bf16 ----------------
__global__ __launch_bounds__(256) void xcvt_kernel(const float* __restrict__ xf, u16* __restrict__ xb)
{
    int i = blockIdx.x*256 + threadIdx.x;     // i < BTv*Cv/4
    float4 v = ((const float4*)xf)[i];
    ((uint2*)xb)[i] = make_uint2(pk2bf(v.x,v.y), pk2bf(v.z,v.w));
}

// ---------------- bf16 MFMA GEMM (m97-style + XCD chunk swizzle) ----------------
// Y[M,N] = X[M,K]*W[N,K]^T, f32 out. BK=64, gload_lds w16 pre-swizzled src; 1D grid.
template<int BM, int BN>
__global__ __launch_bounds__(256) void gemm_bf16_kernel(
    const u16* __restrict__ X, const u16* __restrict__ W, float* __restrict__ Y,
    int M, int N, int K)
{
    constexpr int MR = BM/32, NR = BN/32;
    constexpr int ACALLS = (BM*8)/256, BCALLS = (BN*8)/256;
    __shared__ __align__(16) u16 As[BM*64];
    __shared__ __align__(16) u16 Bs[BN*64];
    int tid = threadIdx.x;
    int wv = tid >> 6, lane = tid & 63;
    int wr = wv >> 1, wc = wv & 1;
    int c = lane & 15, g = lane >> 4;

    // bijective XCD chunk swizzle (m204): contiguous wg range per XCD, N-tile-major
    int mtiles = M / BM;
    int nwg = gridDim.x;
    int qd = nwg >> 3, rr_ = nwg & 7;
    int xcd = blockIdx.x & 7, idx = blockIdx.x >> 3;
    int wg = (xcd < rr_ ? xcd*(qd+1) : rr_*(qd+1) + (xcd-rr_)*qd) + idx;
    int bm = (wg % mtiles) * BM, bn = (wg / mtiles) * BN;

    int r_ = tid >> 3, s_ = tid & 7;

    f32x4 acc[MR][NR];
#pragma unroll
    for (int i=0;i<MR;++i)
#pragma unroll
        for (int j=0;j<NR;++j) acc[i][j] = (f32x4){0.f,0.f,0.f,0.f};

    for (int k0 = 0; k0 < K; k0 += 64) {
#pragma unroll
        for (int i=0;i<ACALLS;++i) {
            int row = i*32 + r_;
            GLOAD16(X + (size_t)(bm+row)*K + k0 + ((s_ ^ (row&7))*8),
                    (u16*)As + i*2048 + wv*512);
        }
#pragma unroll
        for (int i=0;i<BCALLS;++i) {
            int row = i*32 + r_;
            GLOAD16(W + (size_t)(bn+row)*K + k0 + ((s_ ^ (row&7))*8),
                    (u16*)Bs + i*2048 + wv*512);
        }
        __syncthreads();          // drains vmcnt(0): tile landed
#pragma unroll
        for (int kh=0; kh<2; ++kh) {
            short8 a[MR], b[NR];
#pragma unroll
            for (int i=0;i<MR;++i) {
                int row = wr*(BM/2) + i*16 + c;
                a[i] = *(const short8*)&As[row*64 + (((kh*4+g) ^ (c&7))*8)];
            }
#pragma unroll
            for (int j=0;j<NR;++j) {
                int row = wc*(BN/2) + j*16 + c;
                b[j] = *(const short8*)&Bs[row*64 + (((kh*4+g) ^ (c&7))*8)];
            }
#pragma unroll
            for (int i=0;i<MR;++i)
#pragma unroll
                for (int j=0;j<NR;++j)
                    acc[i][j] = __builtin_amdgcn_mfma_f32_16x16x32_bf16(a[i], b[j], acc[i][j], 0,0,0);
        }
        __syncthreads();          // all reads done before next stage overwrites
    }
#pragma unroll
    for (int i=0;i<MR;++i)
#pragma unroll
        for (int j=0;j<NR;++j)
#pragma unroll
            for (int rr=0;rr<4;++rr)
                Y[(size_t)(bm + wr*(BM/2) + i*16 + g*4 + rr)*N + bn + wc*(BN/2) + j*16 + c] = acc[i][j][rr];
}

// ---------------- gates + RoPE + RMS-norm + k time-shift -> bf16 [b,h,t,d] ----------------
__global__ __launch_bounds__(256) void post_kernel(
    const float* __restrict__ x, const float* __restrict__ ve,
    const float* __restrict__ cosT, const float* __restrict__ sinT,
    const float* __restrict__ vegw, const float* __restrict__ atgw,
    float* __restrict__ qkv, float* __restrict__ gateA,
    u16* __restrict__ qbf, u16* __restrict__ kbf)
{
    int bt = blockIdx.x;
    int b = bt >> 11;
    int t = bt & (Tv-1);
    int wave = threadIdx.x >> 6;
    int lane = threadIdx.x & 63;
    int h = blockIdx.y*4 + wave;
    size_t base = (size_t)bt*3072 + h*DHv;
    size_t bh = (size_t)b*Hv + h;

    float gv  = (lane < 32) ? x[(size_t)bt*Cv + lane] * vegw[h*32 + lane] : 0.f;
    float gaP = (lane < 12) ? x[(size_t)bt*Cv + lane] * atgw[h*12 + lane] : 0.f;
#pragma unroll
    for (int off=32; off; off>>=1) {
        gv  += __shfl_xor(gv,  off);
        gaP += __shfl_xor(gaP, off);
    }
    float gateV = 2.f / (1.f + expf(-gv));
    float ga    = 1.f / (1.f + expf(-gaP));
    if (lane == 0) gateA[(size_t)bt*Hv + h] = ga;

    qkv[base + 2048 + lane] += gateV * ve[(size_t)bt*Cv + h*DHv + lane];

    float cs = cosT[t*32 + (lane & 31)];
    float sn = sinT[t*32 + (lane & 31)];

    float qa = qkv[base + lane];
    float qb = __shfl_xor(qa, 32);
    float qr = qa*cs + ((lane < 32) ? qb*sn : -qb*sn);
    float ss = qr*qr;
#pragma unroll
    for (int off=32; off; off>>=1) ss += __shfl_xor(ss, off);
    float qn = qr * rsqrtf(ss*(1.f/64.f) + 1e-6f);
    qbf[(bh*Tv + t)*DHv + lane] = f2bf(qn);

    float ka = qkv[base + 1024 + lane];
    float kb = __shfl_xor(ka, 32);
    float kr = ka*cs + ((lane < 32) ? kb*sn : -kb*sn);
    float s2 = kr*kr;
#pragma unroll
    for (int off=32; off; off>>=1) s2 += __shfl_xor(s2, off);
    float kn = kr * rsqrtf(s2*(1.f/64.f) + 1e-6f);
    if (lane < 32) {
        kbf[(bh*Tv + t)*DHv + lane] = f2bf(kn);
    } else {
        if (t == 0)   kbf[(bh*Tv + 0)*DHv + lane] = f2bf(kn);
        if (t+1 < Tv) kbf[(bh*Tv + t + 1)*DHv + lane] = f2bf(kn);
    }
}

// ---------------- V transpose: f32 qkv v-part -> bf16 [b,h,d,t] ----------------
__global__ __launch_bounds__(256) void vt_kernel(
    const float* __restrict__ qkv, u16* __restrict__ vT)
{
    __shared__ float Ls[64][65];
    int t0 = blockIdx.x * 64;
    int h  = blockIdx.y;
    int b  = blockIdx.z;
    int tid = threadIdx.x;
    for (int i = tid; i < 4096; i += 256) {
        int tt = i >> 6, d = i & 63;
        Ls[tt][d] = qkv[((size_t)(b*Tv + t0 + tt))*3072 + 2048 + h*DHv + d];
    }
    __syncthreads();
    size_t ob = ((size_t)(b*Hv + h))*DHv;
    for (int i = tid; i < 4096; i += 256) {
        int dv = i >> 6, tt = i & 63;
        vT[(ob + dv)*Tv + t0 + tt] = f2bf(Ls[tt][dv]);
    }
}

// ---------------- MFMA flash attention: counted-vmcnt pipeline (T3/T4) ----------------
// 4 waves x 32 q-rows; next K/V tile's gload_lds stay in flight across compute.
__global__ __launch_bounds__(256) void attn_mfma_kernel(
    const u16* __restrict__ qbf, const u16* __restrict__ kbf,
    const u16* __restrict__ vT, const float* __restrict__ gateA,
    u16* __restrict__ ybf, const int* __restrict__ wptr)
{
    __shared__ __align__(16) u16 Ks[2][64*64];
    __shared__ __align__(16) u16 Vt[2][64*64];
    __shared__ __align__(16) u16 Pl[4][32][76];   // 52224 B total

    int qtile = (int)gridDim.x - 1 - (int)blockIdx.x;   // longest-first
    int h = blockIdx.y, b = blockIdx.z;
    int tid = threadIdx.x, wvi = tid >> 6, lane = tid & 63;
    int c = lane & 15, g = lane >> 4;
    int qbase = qtile*128 + wvi*32;
    int wsz = *wptr;
    bool use_w = !(wsz < 0 || wsz >= Tv-1);

    size_t bh = (size_t)b*Hv + h;
    const u16* qb = qbf + (bh*(size_t)Tv + qbase)*DHv;
    short8 A[2][2];
#pragma unroll
    for (int rb=0; rb<2; ++rb)
#pragma unroll
        for (int kh=0; kh<2; ++kh)
            A[rb][kh] = *(const short8*)(qb + (size_t)(rb*16+c)*DHv + kh*32 + g*8);

    f32x4 zero4 = {0.f,0.f,0.f,0.f};
    f32x4 O[2][4], L[2];
#pragma unroll
    for (int rb=0;rb<2;++rb){ L[rb]=zero4;
#pragma unroll
        for (int dg=0;dg<4;++dg) O[rb][dg]=zero4; }

    short8 ONES;
#pragma unroll
    for (int i=0;i<8;++i) ONES[i] = (short)0x3F80;   // bf16 1.0

    int kt_hi = qtile*2 + 1;
    int kt_lo = 0;
    if (use_w) { int lo = qtile*128 - wsz; if (lo > 0) kt_lo = lo >> 6; }
    const float C1 = 0.18033688f;    // 0.125 * log2(e)
    const float C2 = -11.5415606f;   // -8 * log2(e)

    const u16* gK = kbf + bh*(size_t)Tv*DHv;
    const u16* gV = vT  + bh*(size_t)(DHv*Tv);
    int r_ = tid >> 3, s_ = tid & 7;
    int r0 = r_, r1 = r_ + 32;

    auto stage = [&](int buf, int kt) {   // async: 4 gload_lds per wave, pre-swizzled src
        GLOAD16(gK + (size_t)kt*4096 + r0*64 + ((s_ ^ (r0&7))*8), (u16*)&Ks[buf][0] + wvi*512);
        GLOAD16(gK + (size_t)kt*4096 + r1*64 + ((s_ ^ (r1&7))*8), (u16*)&Ks[buf][0] + 2048 + wvi*512);
        GLOAD16(gV + (size_t)r0*Tv + kt*64 + ((s_ ^ (r0&7))*8),   (u16*)&Vt[buf][0] + wvi*512);
        GLOAD16(gV + (size_t)r1*Tv + kt*64 + ((s_ ^ (r1&7))*8),   (u16*)&Vt[buf][0] + 2048 + wvi*512);
    };

    auto compute = [&](int kt, int cur) {
        short8 Bk[4][2];
#pragma unroll
        for (int kg=0;kg<4;++kg)
#pragma unroll
            for (int kh=0;kh<2;++kh)
                Bk[kg][kh] = *(const short8*)&Ks[cur][(kg*16+c)*64 + (((kh*4+g) ^ (c&7))*8)];
        f32x4 S[2][4];
        __builtin_amdgcn_s_setprio(1);
#pragma unroll
        for (int rb=0;rb<2;++rb)
#pragma unroll
            for (int kg=0;kg<4;++kg) {
                S[rb][kg] = __builtin_amdgcn_mfma_f32_16x16x32_bf16(A[rb][0], Bk[kg][0], zero4, 0,0,0);
                S[rb][kg] = __builtin_amdgcn_mfma_f32_16x16x32_bf16(A[rb][1], Bk[kg][1], S[rb][kg], 0,0,0);
            }
        __builtin_amdgcn_s_setprio(0);
        bool needmask = (kt*64 + 63 > qbase) || (use_w && (kt*64 < qbase + 31 - wsz));
#pragma unroll
        for (int rb=0;rb<2;++rb)
#pragma unroll
            for (int kg=0;kg<4;++kg)
#pragma unroll
                for (int r=0;r<4;++r) {
                    float t = fmaf(S[rb][kg][r], C1, C2);   // exp2 domain
                    if (needmask) {
                        int key = kt*64 + kg*16 + c;
                        int qg  = qbase + rb*16 + g*4 + r;
                        bool ok = (key <= qg) && (!use_w || (qg - key <= wsz));
                        t = ok ? t : -1e30f;
                    }
                    Pl[wvi][rb*16 + g*4 + r][kg*16 + c] = f2bf(fexp2(t));
                }
        asm volatile("s_waitcnt lgkmcnt(0)" ::: "memory");
        __builtin_amdgcn_sched_barrier(0);
        short8 Vf[4][2];
#pragma unroll
        for (int dg=0;dg<4;++dg)
#pragma unroll
            for (int kh=0;kh<2;++kh)
                Vf[dg][kh] = *(const short8*)&Vt[cur][(dg*16+c)*64 + (((kh*4+g) ^ (c&7))*8)];
        __builtin_amdgcn_s_setprio(1);
#pragma unroll
        for (int rb=0;rb<2;++rb) {
            short8 PA0 = *(const short8*)&Pl[wvi][rb*16+c][g*8];
            short8 PA1 = *(const short8*)&Pl[wvi][rb*16+c][32 + g*8];
            L[rb] = __builtin_amdgcn_mfma_f32_16x16x32_bf16(PA0, ONES, L[rb], 0,0,0);
            L[rb] = __builtin_amdgcn_mfma_f32_16x16x32_bf16(PA1, ONES, L[rb], 0,0,0);
#pragma unroll
            for (int dg=0;dg<4;++dg) {
                O[rb][dg] = __builtin_amdgcn_mfma_f32_16x16x32_bf16(PA0, Vf[dg][0], O[rb][dg], 0,0,0);
                O[rb][dg] = __builtin_amdgcn_mfma_f32_16x16x32_bf16(PA1, Vf[dg][1], O[rb][dg], 0,0,0);
            }
        }
        __builtin_amdgcn_s_setprio(0);
    };

    // ---- counted-vmcnt double-buffer: next tile's loads fly across compute ----
    stage(0, kt_lo);
    if (kt_lo + 1 <= kt_hi) stage(1, kt_lo + 1);
    int cur = 0;
    for (int kt = kt_lo; kt <= kt_hi; ++kt) {
        if (kt < kt_hi) { asm volatile("s_waitcnt vmcnt(4)" ::: "memory"); }
        else            { asm volatile("s_waitcnt vmcnt(0)" ::: "memory"); }
        __builtin_amdgcn_s_barrier();      // all waves' cur-tile loads landed
        compute(kt, cur);                  // lgkm drained before MFMA consumers
        __builtin_amdgcn_s_barrier();      // all waves done reading cur
        if (kt + 2 <= kt_hi) stage(cur, kt + 2);
        cur ^= 1;
    }

    float gar[2][4], linv[2][4];
#pragma unroll
    for (int rb=0;rb<2;++rb)
#pragma unroll
        for (int r=0;r<4;++r) {
            gar[rb][r]  = gateA[(size_t)(b*Tv + qbase + rb*16 + g*4 + r)*Hv + h];
            linv[rb][r] = 1.f / L[rb][r];
        }
#pragma unroll
    for (int rb=0;rb<2;++rb)
#pragma unroll
        for (int dg=0;dg<4;++dg)
#pragma unroll
            for (int r=0;r<4;++r)
                ybf[((size_t)(b*Tv + qbase + rb*16 + g*4 + r))*Cv + h*DHv + dg*16 + c] =
                    f2bf(O[rb][dg][r] * linv[rb][r] * gar[rb][r]);
}

extern "C" void kernel_launch(void* const* d_in, const int* in_sizes, int n_in,
                              void* d_out, int out_size, void* d_ws, size_t ws_size,
                              hipStream_t stream) {
    const float* x    = (const float*)d_in[0];
    const float* ve   = (const float*)d_in[1];
    const float* cosT = (const float*)d_in[2];
    const float* sinT = (const float*)d_in[3];
    const float* cqw  = (const float*)d_in[4];
    const float* ckw  = (const float*)d_in[5];
    const float* cvw  = (const float*)d_in[6];
    const float* cpw  = (const float*)d_in[7];
    const float* vegw = (const float*)d_in[8];
    const float* atgw = (const float*)d_in[9];
    const float* qmix = (const float*)d_in[10];
    const float* kmix = (const float*)d_in[11];
    const float* vmix = (const float*)d_in[12];
    const int*   wsz  = (const int*)d_in[13];
    float* out = (float*)d_out;

    const size_t M1 = 1u << 20;
    float* p0 = (float*)d_ws;
    // layout (float units): [0,12M) qkv f32 | [12M,12.5M) cpj bf16 | [12.5M,12.57M) ga
    // | [13M,15M) qbf | [15M,17M) kbf | [17M,19M) vT
    // phase-A aliases: whi bf16 at [13M,14.5M); xbf bf16 at [15M,17M)
    // phase-C alias:   ybf bf16 at [0,2M)
    float* qkv = p0;
    u16*   cpj = (u16*)(p0 + 12*M1);
    float* ga  = p0 + 12*M1 + M1/2;
    u16*   qbf = (u16*)(p0 + 13*M1);
    u16*   kbf = (u16*)(p0 + 15*M1);
    u16*   vT  = (u16*)(p0 + 17*M1);
    u16*   whi = (u16*)(p0 + 13*M1);
    u16*   xbf = (u16*)(p0 + 15*M1);
    u16*   ybf = (u16*)p0;

    fuse_w_kernel<<<208, 256, 0, stream>>>(cqw, ckw, cvw, cpw, qmix, kmix, vmix, whi, cpj);
    xcvt_kernel<<<(BTv*Cv/4)/256, 256, 0, stream>>>(x, xbf);

    gemm_bf16_kernel<128,128><<<(3072/128)*(BTv/128), 256, 0, stream>>>(
        xbf, whi, qkv, BTv, 3072, Cv);

    post_kernel<<<dim3(BTv, Hv/4), 256, 0, stream>>>(x, ve, cosT, sinT, vegw, atgw,
                                                     qkv, ga, qbf, kbf);

    vt_kernel<<<dim3(Tv/64, Hv, Bv), 256, 0, stream>>>(qkv, vT);

    attn_mfma_kernel<<<dim3(Tv/128, Hv, Bv), 256, 0, stream>>>(qbf, kbf, vT, ga, ybf, wsz);

    gemm_bf16_kernel<128,64><<<(Cv/64)*(BTv/128), 256, 0, stream>>>(
        ybf, cpj, out, BTv, Cv, Cv);
}